// Round 6
// baseline (299.393 us; speedup 1.0000x reference)
//
#include <hip/hip_runtime.h>
#include <math.h>

#define NN 4096      // nodes
#define CC 512       // concat dim = 8 heads * 64
#define MB (1024*1024)
#define LOG2E 1.4426950408889634f

typedef __attribute__((ext_vector_type(8))) __bf16 bf16x8;
typedef __attribute__((ext_vector_type(4))) float f32x4;
typedef unsigned short ushort_t;
typedef unsigned int uint_t;
typedef unsigned char uchar_t;

#if __has_builtin(__builtin_amdgcn_exp2f)
#define EXP2(x) __builtin_amdgcn_exp2f(x)
#else
#define EXP2(x) exp2f(x)
#endif

static __device__ __forceinline__ float elu1(float x){ return x > 0.f ? x : (__expf(x)-1.f); }
static __device__ __forceinline__ ushort_t f2bf(float f){
    union { float f; uint_t u; } v; v.f = f;
    uint_t r = (v.u + 0x7FFFu + ((v.u >> 16) & 1u)) >> 16;
    return (ushort_t)r;
}
static __device__ __forceinline__ float bf2f(ushort_t h){
    union { uint_t u; float f; } q; q.u = ((uint_t)h) << 16; return q.f;
}

// ---- prep W: W_att [8][512(k)][64(f)] -> Wh/Wl [512(c)][512(k)] bf16 hi/lo
__global__ void k_prepW(const float* __restrict__ Watt,
                        ushort_t* __restrict__ Wh, ushort_t* __restrict__ Wl){
    int idx = blockIdx.x*256 + threadIdx.x;     // < 512*128
    int c = idx >> 7, kq = idx & 127, k = kq*4;
    ushort4 h4, l4;
    float v[4];
    #pragma unroll
    for(int j=0;j<4;j++)
        v[j] = Watt[(c>>6)*(512*64) + (k+j)*64 + (c&63)];
    h4.x = f2bf(v[0]); h4.y = f2bf(v[1]); h4.z = f2bf(v[2]); h4.w = f2bf(v[3]);
    l4.x = f2bf(v[0]-bf2f(h4.x)); l4.y = f2bf(v[1]-bf2f(h4.y));
    l4.z = f2bf(v[2]-bf2f(h4.z)); l4.w = f2bf(v[3]-bf2f(h4.w));
    *(ushort4*)&Wh[(size_t)c*512 + k] = h4;
    *(ushort4*)&Wl[(size_t)c*512 + k] = l4;
}

// ---- split x [4096][512] f32 -> xh/xl bf16
__global__ void k_splitx(const float* __restrict__ x,
                         ushort_t* __restrict__ xh, ushort_t* __restrict__ xl){
    int idx = blockIdx.x*256 + threadIdx.x;     // < 4096*512/4
    float4 v = *(const float4*)&x[(size_t)idx*4];
    ushort4 h4, l4;
    h4.x = f2bf(v.x); h4.y = f2bf(v.y); h4.z = f2bf(v.z); h4.w = f2bf(v.w);
    l4.x = f2bf(v.x-bf2f(h4.x)); l4.y = f2bf(v.y-bf2f(h4.y));
    l4.z = f2bf(v.z-bf2f(h4.z)); l4.w = f2bf(v.w-bf2f(h4.w));
    *(ushort4*)&xh[(size_t)idx*4] = h4;
    *(ushort4*)&xl[(size_t)idx*4] = l4;
}

// ---- pack adjacency to bits
__global__ void k_pack(const int* __restrict__ adj, uint_t* __restrict__ abits){
    int idx = blockIdx.x*256 + threadIdx.x;            // < 4096*128
    int i = idx >> 7, q = idx & 127;
    const int4* p = (const int4*)&adj[(size_t)i*NN + q*32];
    uint_t m = 0;
    #pragma unroll
    for(int g=0; g<8; g++){
        int4 v = p[g];
        m |= (uint_t)(v.x > 0) << (g*4 + 0);
        m |= (uint_t)(v.y > 0) << (g*4 + 1);
        m |= (uint_t)(v.z > 0) << (g*4 + 2);
        m |= (uint_t)(v.w > 0) << (g*4 + 3);
    }
    abits[idx] = m;
}

// ---- gemm1 via MFMA (bf16 hi/lo split): h = x @ W_all
// grid (64, 8), block 256 = 4 waves. Wave: rows i0+wv*16..+16, cols j0..+64.
// Writes h_all f32 [4096][512] AND hT bf16 [512][4096].
__global__ __launch_bounds__(256) void k_gemm1(
        const ushort_t* __restrict__ xh, const ushort_t* __restrict__ xl,
        const ushort_t* __restrict__ Wh, const ushort_t* __restrict__ Wl,
        float* __restrict__ h_all, ushort_t* __restrict__ hT){
    const int t = threadIdx.x;
    const int l = t & 63, wv = t >> 6;
    const int lr = l & 15, lg = l >> 4;
    const int ib = blockIdx.x*64 + wv*16;
    const int j0 = blockIdx.y*64;

    f32x4 acc[4] = {};
    #pragma unroll 2
    for(int ks=0; ks<16; ks++){
        const int kb = ks*32 + lg*8;
        bf16x8 ah = *(const bf16x8*)&xh[(size_t)(ib+lr)*512 + kb];
        bf16x8 al = *(const bf16x8*)&xl[(size_t)(ib+lr)*512 + kb];
        bf16x8 bh[4], bl[4];
        #pragma unroll
        for(int nt=0;nt<4;nt++){
            bh[nt] = *(const bf16x8*)&Wh[(size_t)(j0+nt*16+lr)*512 + kb];
            bl[nt] = *(const bf16x8*)&Wl[(size_t)(j0+nt*16+lr)*512 + kb];
        }
        #pragma unroll
        for(int nt=0;nt<4;nt++){
            acc[nt] = __builtin_amdgcn_mfma_f32_16x16x32_bf16(ah, bh[nt], acc[nt], 0,0,0);
            acc[nt] = __builtin_amdgcn_mfma_f32_16x16x32_bf16(al, bh[nt], acc[nt], 0,0,0);
            acc[nt] = __builtin_amdgcn_mfma_f32_16x16x32_bf16(ah, bl[nt], acc[nt], 0,0,0);
        }
    }
    #pragma unroll
    for(int nt=0;nt<4;nt++){
        const int col = j0 + nt*16 + lr;
        #pragma unroll
        for(int r=0;r<4;r++)
            h_all[(size_t)(ib + lg*4 + r)*512 + col] = acc[nt][r];
        ushort4 o;
        o.x = f2bf(acc[nt][0]); o.y = f2bf(acc[nt][1]);
        o.z = f2bf(acc[nt][2]); o.w = f2bf(acc[nt][3]);
        *(ushort4*)&hT[(size_t)col*NN + ib + lg*4] = o;
    }
}

// ---- scores layer1 (pre-scaled by log2e)
__global__ void k_scores1(const float* __restrict__ hall, const float* __restrict__ aatt,
                          float* __restrict__ ssrc2, float* __restrict__ sdst2){
    int t = threadIdx.x;
    int hd = t & 7, il = t >> 3;
    int i = blockIdx.x*32 + il;
    const float4* h4 = (const float4*)&hall[(size_t)i*CC + hd*64];
    const float4* a1 = (const float4*)&aatt[hd*128];
    const float4* a2 = (const float4*)&aatt[hd*128 + 64];
    float ss = 0.f, sd = 0.f;
    #pragma unroll
    for(int q=0;q<16;q++){
        float4 h = h4[q], u = a1[q], v = a2[q];
        ss += h.x*u.x + h.y*u.y + h.z*u.z + h.w*u.w;
        sd += h.x*v.x + h.y*v.y + h.z*v.z + h.w*v.w;
    }
    ssrc2[hd*NN + i] = ss*LOG2E;
    sdst2[hd*NN + i] = sd*LOG2E;
}

// ---- attention layer1 via MFMA, 2-deep pipeline, head-pair blocks.
// grid (128, 2, 4): i-block, j-chunk (2048), head-pair. block 256 = 4 waves.
// Waves split the j-chunk 4-way (512 j each, 16 jt); LDS-reduce epilogue.
__global__ __launch_bounds__(256) void k_attn1(
        const ushort_t* __restrict__ hT,
        const float* __restrict__ ssrc2, const float* __restrict__ sdst2,
        const uchar_t* __restrict__ abits,
        float* __restrict__ pnumT, float* __restrict__ pden){
    const int t = threadIdx.x;
    const int l = t & 63, wv = t >> 6;
    const int hd0 = blockIdx.z*2;
    const int i0 = blockIdx.x*32;
    const int jcc = blockIdx.y;
    const int lr = l & 15, lg = l >> 4;

    f32x4 acc[2][2][4] = {};   // [hd][mh][nt]
    f32x4 dacc[2][2] = {};

    float ss[2][2];
    #pragma unroll
    for(int hd=0;hd<2;hd++)
        #pragma unroll
        for(int mh=0;mh<2;mh++)
            ss[hd][mh] = ssrc2[(hd0+hd)*NN + i0 + mh*16 + lr];

    bf16x8 ones;
    #pragma unroll
    for(int e=0;e<8;e++) ones[e] = (__bf16)1.0f;

    const int jwb = jcc*2048 + wv*512;                 // wave's j base
    const uchar_t* arow0 = &abits[(size_t)(i0 + lr)*512 + jcc*256 + wv*64];
    const uchar_t* arow1 = &abits[(size_t)(i0 + 16 + lr)*512 + jcc*256 + wv*64];

    bf16x8 bA[2][4], bB[2][4];
    float4 sdaA[2], sdbA[2], sdaB[2], sdbB[2];
    uint_t bitsA0, bitsA1, bitsB0, bitsB1;

#define LOAD1(SFX, JT) { \
    const int jb_ = jwb + (JT)*32 + lg*8; \
    _Pragma("unroll") \
    for(int hd=0;hd<2;hd++){ \
        _Pragma("unroll") \
        for(int nt=0;nt<4;nt++) \
            b##SFX[hd][nt] = *(const bf16x8*)&hT[(size_t)((hd0+hd)*64 + nt*16 + lr)*NN + jb_]; \
        sda##SFX[hd] = *(const float4*)&sdst2[(hd0+hd)*NN + jb_]; \
        sdb##SFX[hd] = *(const float4*)&sdst2[(hd0+hd)*NN + jb_ + 4]; \
    } \
    bits##SFX##0 = arow0[(JT)*4 + lg]; \
    bits##SFX##1 = arow1[(JT)*4 + lg]; }

#define COMP1(SFX) { \
    _Pragma("unroll") \
    for(int hd=0;hd<2;hd++){ \
        float sdv[8] = {sda##SFX[hd].x, sda##SFX[hd].y, sda##SFX[hd].z, sda##SFX[hd].w, \
                        sdb##SFX[hd].x, sdb##SFX[hd].y, sdb##SFX[hd].z, sdb##SFX[hd].w}; \
        _Pragma("unroll") \
        for(int mh=0;mh<2;mh++){ \
            const uint_t bits = mh ? bits##SFX##1 : bits##SFX##0; \
            bf16x8 a; \
            _Pragma("unroll") \
            for(int e=0;e<8;e++){ \
                float s_ = ss[hd][mh] + sdv[e]; \
                float t_ = fmaxf(s_, 0.2f*s_); \
                float w_ = EXP2(t_) * (float)((bits >> e) & 1u); \
                a[e] = (__bf16)w_; \
            } \
            _Pragma("unroll") \
            for(int nt=0;nt<4;nt++) \
                acc[hd][mh][nt] = __builtin_amdgcn_mfma_f32_16x16x32_bf16( \
                    a, b##SFX[hd][nt], acc[hd][mh][nt], 0, 0, 0); \
            dacc[hd][mh] = __builtin_amdgcn_mfma_f32_16x16x32_bf16( \
                    a, ones, dacc[hd][mh], 0, 0, 0); \
        } \
    } }

    LOAD1(A, 0);
    for(int jt=0; jt<16; jt+=2){
        LOAD1(B, jt+1);
        COMP1(A);
        if (jt + 2 < 16) LOAD1(A, jt+2);
        COMP1(B);
    }
#undef LOAD1
#undef COMP1

    // cross-wave reduction in LDS: slots 0..15 = acc[(hd*2+mh)*4+nt], 16..19 = dacc
    __shared__ f32x4 red[2][20][64];
    __syncthreads();
    if (wv >= 2){
        #pragma unroll
        for(int hd=0;hd<2;hd++)
            #pragma unroll
            for(int mh=0;mh<2;mh++){
                #pragma unroll
                for(int nt=0;nt<4;nt++) red[wv-2][(hd*2+mh)*4+nt][l] = acc[hd][mh][nt];
                red[wv-2][16 + hd*2+mh][l] = dacc[hd][mh];
            }
    }
    __syncthreads();
    if (wv < 2){
        #pragma unroll
        for(int hd=0;hd<2;hd++)
            #pragma unroll
            for(int mh=0;mh<2;mh++){
                #pragma unroll
                for(int nt=0;nt<4;nt++) acc[hd][mh][nt] += red[wv][(hd*2+mh)*4+nt][l];
                dacc[hd][mh] += red[wv][16 + hd*2+mh][l];
            }
    }
    __syncthreads();
    if (wv == 1){
        #pragma unroll
        for(int hd=0;hd<2;hd++)
            #pragma unroll
            for(int mh=0;mh<2;mh++){
                #pragma unroll
                for(int nt=0;nt<4;nt++) red[0][(hd*2+mh)*4+nt][l] = acc[hd][mh][nt];
                red[0][16 + hd*2+mh][l] = dacc[hd][mh];
            }
    }
    __syncthreads();
    if (wv == 0){
        #pragma unroll
        for(int hd=0;hd<2;hd++)
            #pragma unroll
            for(int mh=0;mh<2;mh++){
                #pragma unroll
                for(int nt=0;nt<4;nt++){
                    f32x4 v = acc[hd][mh][nt] + red[0][(hd*2+mh)*4+nt][l];
                    int col = (hd0+hd)*64 + nt*16 + lr;
                    float4 o = {v[0], v[1], v[2], v[3]};
                    *(float4*)&pnumT[((size_t)jcc*512 + col)*NN + i0 + mh*16 + lg*4] = o;
                }
                f32x4 d = dacc[hd][mh] + red[0][16 + hd*2+mh][l];
                if (lr == 0){
                    #pragma unroll
                    for(int r=0;r<4;r++)
                        pden[((size_t)jcc*8 + hd0+hd)*NN + i0 + mh*16 + lg*4 + r] = d[r];
                }
            }
    }
}

// ---- reduce layer1: hcatT[c][i] = elu( sum_jc pnumT / sum_jc pden )
__global__ void k_reduce1T(const float* __restrict__ pnumT, const float* __restrict__ pden,
                           float* __restrict__ hcatT){
    int idx = blockIdx.x*256 + threadIdx.x;           // < 512*4096
    int c = idx >> 12, i = idx & 4095, hd = c >> 6;
    float s = 0.f, d = 0.f;
    #pragma unroll
    for(int jc=0;jc<2;jc++){
        s += pnumT[((size_t)jc*512 + c)*NN + i];
        d += pden[((size_t)jc*8 + hd)*NN + i];
    }
    hcatT[(size_t)c*NN + i] = elu1(s/d);
}

// ---- gemm2 fused: h2 = hcat @ Wout; emits h2T bf16 + ss2/sd2 (scores, *log2e)
__global__ __launch_bounds__(256) void k_gemm2(const float* __restrict__ AT,
                                               const float* __restrict__ B,
                                               const float* __restrict__ aout,
                                               ushort_t* __restrict__ h2T,
                                               float* __restrict__ ss2,
                                               float* __restrict__ sd2){
    __shared__ float As[32][32];   // [k][i]
    __shared__ float Bs[32][32];   // [k][n]
    const int t = threadIdx.x;
    const int i0 = blockIdx.x*32;
    const int ty = t >> 4, tx = t & 15;
    float acc[2][2] = {{0.f,0.f},{0.f,0.f}};
    for(int k0=0;k0<512;k0+=32){
        __syncthreads();
        { int k = t >> 3, i4 = (t & 7)*4;
          *(float4*)&As[k][i4] = *(const float4*)&AT[(size_t)(k0+k)*NN + i0 + i4]; }
        { int k = t >> 3, n4 = (t & 7)*4;
          *(float4*)&Bs[k][n4] = *(const float4*)&B[(size_t)(k0+k)*32 + n4]; }
        __syncthreads();
        #pragma unroll
        for(int k=0;k<32;k++){
            float2 a2 = *(const float2*)&As[k][ty*2];
            float2 b2 = *(const float2*)&Bs[k][tx*2];
            acc[0][0] += a2.x*b2.x; acc[0][1] += a2.x*b2.y;
            acc[1][0] += a2.y*b2.x; acc[1][1] += a2.y*b2.y;
        }
    }
    // h2T bf16 writes
    #pragma unroll
    for(int a=0;a<2;a++){
        #pragma unroll
        for(int b=0;b<2;b++)
            h2T[(size_t)(tx*2+b)*NN + i0 + ty*2 + a] = f2bf(acc[a][b]);
    }
    // fused scores: reduce over tx (16 lanes)
    float a1x = aout[tx*2], a1y = aout[tx*2+1];
    float a2x = aout[32+tx*2], a2y = aout[32+tx*2+1];
    #pragma unroll
    for(int a=0;a<2;a++){
        float ps = acc[a][0]*a1x + acc[a][1]*a1y;
        float pd = acc[a][0]*a2x + acc[a][1]*a2y;
        #pragma unroll
        for(int m=1;m<16;m<<=1){
            ps += __shfl_xor(ps, m);
            pd += __shfl_xor(pd, m);
        }
        if (tx == 0){
            ss2[i0 + ty*2 + a] = ps*LOG2E;
            sd2[i0 + ty*2 + a] = pd*LOG2E;
        }
    }
}

// ---- attention layer2 via MFMA, 2-deep pipeline. grid (256,4), 4 waves,
// wave covers disjoint j-subtile. jcw = jc*4+wv (16 partials). pnum2T [16][32][4096].
__global__ __launch_bounds__(256) void k_attn2(
        const ushort_t* __restrict__ h2T,
        const float* __restrict__ ss2, const float* __restrict__ sd2,
        const uchar_t* __restrict__ abits,
        float* __restrict__ pnum2T, float* __restrict__ pden2){
    const int t = threadIdx.x;
    const int l = t & 63;
    const int wv = t >> 6;
    const int i0 = blockIdx.x*16;
    const int jc = blockIdx.y;
    const int lr = l & 15, lg = l >> 4;
    const int jcw = jc*4 + wv;

    f32x4 acc[2] = {};
    f32x4 dacc = {};
    const float ss = ss2[i0 + lr];
    bf16x8 ones;
    #pragma unroll
    for(int e=0;e<8;e++) ones[e] = (__bf16)1.0f;

    const uchar_t* arow = &abits[(size_t)(i0+lr)*512 + jc*128 + wv*4];

    bf16x8 bA[2], bB[2];
    float4 sdaA, sdbA, sdaB, sdbB;
    uint_t bitsA, bitsB;

#define LOAD2(SFX, JT) { \
    const int jb_ = jc*1024 + (JT)*128 + wv*32 + lg*8; \
    _Pragma("unroll") \
    for(int nt=0;nt<2;nt++) \
        b##SFX[nt] = *(const bf16x8*)&h2T[(size_t)(nt*16 + lr)*NN + jb_]; \
    sda##SFX = *(const float4*)&sd2[jb_]; \
    sdb##SFX = *(const float4*)&sd2[jb_ + 4]; \
    bits##SFX = arow[(JT)*16 + lg]; }

#define COMP2(SFX) { \
    float sdv[8] = {sda##SFX.x, sda##SFX.y, sda##SFX.z, sda##SFX.w, \
                    sdb##SFX.x, sdb##SFX.y, sdb##SFX.z, sdb##SFX.w}; \
    bf16x8 a; \
    _Pragma("unroll") \
    for(int e=0;e<8;e++){ \
        float s_ = ss + sdv[e]; \
        float t_ = fmaxf(s_, 0.2f*s_); \
        float w_ = EXP2(t_) * (float)((bits##SFX >> e) & 1u); \
        a[e] = (__bf16)w_; \
    } \
    _Pragma("unroll") \
    for(int nt=0;nt<2;nt++) \
        acc[nt] = __builtin_amdgcn_mfma_f32_16x16x32_bf16(a, b##SFX[nt], acc[nt], 0, 0, 0); \
    dacc = __builtin_amdgcn_mfma_f32_16x16x32_bf16(a, ones, dacc, 0, 0, 0); }

    LOAD2(A, 0);
    for(int jt=0; jt<8; jt+=2){
        LOAD2(B, jt+1);
        COMP2(A);
        if (jt + 2 < 8) LOAD2(A, jt+2);
        COMP2(B);
    }
#undef LOAD2
#undef COMP2

    #pragma unroll
    for(int nt=0;nt<2;nt++){
        int col = nt*16 + lr;
        float4 v = {acc[nt][0], acc[nt][1], acc[nt][2], acc[nt][3]};
        *(float4*)&pnum2T[((size_t)jcw*32 + col)*NN + i0 + lg*4] = v;
    }
    if (lr == 0){
        #pragma unroll
        for(int r=0;r<4;r++)
            pden2[(size_t)jcw*NN + i0 + lg*4 + r] = dacc[r];
    }
}

// ---- reduce layer2 -> final output
__global__ void k_reduce2(const float* __restrict__ pnum2T, const float* __restrict__ pden2,
                          float* __restrict__ out){
    int idx = blockIdx.x*256 + threadIdx.x;       // < 32*4096
    int c = idx >> 12, i = idx & 4095;
    float s = 0.f, d = 0.f;
    #pragma unroll
    for(int jcw=0;jcw<16;jcw++){
        s += pnum2T[((size_t)jcw*32 + c)*NN + i];
        d += pden2[(size_t)jcw*NN + i];
    }
    out[(size_t)i*32 + c] = elu1(s/d);
}

extern "C" void kernel_launch(void* const* d_in, const int* in_sizes, int n_in,
                              void* d_out, int out_size, void* d_ws, size_t ws_size,
                              hipStream_t stream){
    const float* x    = (const float*)d_in[0];
    const int*   adj  = (const int*)  d_in[1];
    const float* Watt = (const float*)d_in[2];
    const float* aatt = (const float*)d_in[3];
    const float* Wout = (const float*)d_in[4];
    const float* aout = (const float*)d_in[5];
    float* out = (float*)d_out;
    char* ws = (char*)d_ws;

    float*    h_all = (float*)   (ws + (size_t) 0*MB);  // 8 MB [4096][512]
    float*    hcatT = (float*)   (ws + (size_t) 0*MB);  // overlays dead h_all [512][4096]
    ushort_t* Whi   = (ushort_t*)(ws + (size_t) 8*MB);  // 512 KB [512][512] bf16
    ushort_t* Wlo   = (ushort_t*)(ws + (size_t) 8*MB + 512*1024);  // 512 KB
    float*    ssrc2 = (float*)   (ws + (size_t) 9*MB);  // 128 KB [8][4096]
    float*    sdst2 = (float*)   (ws + (size_t)10*MB);  // 128 KB
    ushort_t* hT    = (ushort_t*)(ws + (size_t)11*MB);  // 4 MB [512][4096] bf16
    uint_t*   abits = (uint_t*)  (ws + (size_t)15*MB);  // 2 MB [4096][128]
    float*    ss2   = (float*)   (ws + (size_t)18*MB);  // 16 KB
    float*    sd2   = (float*)   (ws + (size_t)19*MB);  // 16 KB
    ushort_t* h2T   = (ushort_t*)(ws + (size_t)20*MB);  // 256 KB [32][4096] bf16
    float*    pden  = (float*)   (ws + (size_t)21*MB);  // 256 KB [2][8][4096]
    float*    pden2 = (float*)   (ws + (size_t)21*MB + 512*1024); // 256 KB [16][4096]
    float*    pnumT = (float*)   (ws + (size_t)22*MB);  // 16 MB [2][512][4096]
    float*    pnum2T= pnumT;                            // reused: [16][32][4096] 8MB
    ushort_t* xh    = (ushort_t*)(ws + (size_t)38*MB);  // 4 MB [4096][512] bf16
    ushort_t* xl    = (ushort_t*)(ws + (size_t)42*MB);  // 4 MB
    if (ws_size < (size_t)55*MB) return;                // need 55 MB scratch

    k_prepW   <<<256, 256, 0, stream>>>(Watt, Whi, Wlo);
    k_splitx  <<<2048, 256, 0, stream>>>(x, xh, xl);
    k_pack    <<<2048, 256, 0, stream>>>(adj, abits);
    k_gemm1   <<<dim3(64,8), 256, 0, stream>>>(xh, xl, Whi, Wlo, h_all, hT);
    k_scores1 <<<128, 256, 0, stream>>>(h_all, aatt, ssrc2, sdst2);
    k_attn1   <<<dim3(128,2,4), 256, 0, stream>>>(hT, ssrc2, sdst2, (const uchar_t*)abits, pnumT, pden);
    k_reduce1T<<<8192, 256, 0, stream>>>(pnumT, pden, hcatT);
    k_gemm2   <<<128, 256, 0, stream>>>(hcatT, Wout, aout, h2T, ss2, sd2);
    k_attn2   <<<dim3(256,4), 256, 0, stream>>>(h2T, ss2, sd2, (const uchar_t*)abits, pnum2T, pden2);
    k_reduce2 <<<512, 256, 0, stream>>>(pnum2T, pden2, out);
}

// Round 7
// 262.996 us; speedup vs baseline: 1.1384x; 1.1384x over previous
//
#include <hip/hip_runtime.h>
#include <math.h>

#define NN 4096      // nodes
#define CC 512       // concat dim = 8 heads * 64
#define MB (1024*1024)
#define LOG2E 1.4426950408889634f

typedef __attribute__((ext_vector_type(8))) __bf16 bf16x8;
typedef __attribute__((ext_vector_type(4))) float f32x4;
typedef unsigned short ushort_t;
typedef unsigned int uint_t;
typedef unsigned char uchar_t;

#if __has_builtin(__builtin_amdgcn_exp2f)
#define EXP2(x) __builtin_amdgcn_exp2f(x)
#else
#define EXP2(x) exp2f(x)
#endif

static __device__ __forceinline__ float elu1(float x){ return x > 0.f ? x : (__expf(x)-1.f); }
static __device__ __forceinline__ ushort_t f2bf(float f){
    union { float f; uint_t u; } v; v.f = f;
    uint_t r = (v.u + 0x7FFFu + ((v.u >> 16) & 1u)) >> 16;
    return (ushort_t)r;
}
static __device__ __forceinline__ float bf2f(ushort_t h){
    union { uint_t u; float f; } q; q.u = ((uint_t)h) << 16; return q.f;
}

// ---- prep W: W_att [8][512(k)][64(f)] -> Wh/Wl [512(c)][512(k)] bf16 hi/lo
__global__ void k_prepW(const float* __restrict__ Watt,
                        ushort_t* __restrict__ Wh, ushort_t* __restrict__ Wl){
    int idx = blockIdx.x*256 + threadIdx.x;     // < 512*128
    int c = idx >> 7, kq = idx & 127, k = kq*4;
    ushort4 h4, l4;
    float v[4];
    #pragma unroll
    for(int j=0;j<4;j++)
        v[j] = Watt[(c>>6)*(512*64) + (k+j)*64 + (c&63)];
    h4.x = f2bf(v[0]); h4.y = f2bf(v[1]); h4.z = f2bf(v[2]); h4.w = f2bf(v[3]);
    l4.x = f2bf(v[0]-bf2f(h4.x)); l4.y = f2bf(v[1]-bf2f(h4.y));
    l4.z = f2bf(v[2]-bf2f(h4.z)); l4.w = f2bf(v[3]-bf2f(h4.w));
    *(ushort4*)&Wh[(size_t)c*512 + k] = h4;
    *(ushort4*)&Wl[(size_t)c*512 + k] = l4;
}

// ---- split x [4096][512] f32 -> xh/xl bf16
__global__ void k_splitx(const float* __restrict__ x,
                         ushort_t* __restrict__ xh, ushort_t* __restrict__ xl){
    int idx = blockIdx.x*256 + threadIdx.x;     // < 4096*512/4
    float4 v = *(const float4*)&x[(size_t)idx*4];
    ushort4 h4, l4;
    h4.x = f2bf(v.x); h4.y = f2bf(v.y); h4.z = f2bf(v.z); h4.w = f2bf(v.w);
    l4.x = f2bf(v.x-bf2f(h4.x)); l4.y = f2bf(v.y-bf2f(h4.y));
    l4.z = f2bf(v.z-bf2f(h4.z)); l4.w = f2bf(v.w-bf2f(h4.w));
    *(ushort4*)&xh[(size_t)idx*4] = h4;
    *(ushort4*)&xl[(size_t)idx*4] = l4;
}

// ---- pack adjacency to bits
__global__ void k_pack(const int* __restrict__ adj, uint_t* __restrict__ abits){
    int idx = blockIdx.x*256 + threadIdx.x;            // < 4096*128
    int i = idx >> 7, q = idx & 127;
    const int4* p = (const int4*)&adj[(size_t)i*NN + q*32];
    uint_t m = 0;
    #pragma unroll
    for(int g=0; g<8; g++){
        int4 v = p[g];
        m |= (uint_t)(v.x > 0) << (g*4 + 0);
        m |= (uint_t)(v.y > 0) << (g*4 + 1);
        m |= (uint_t)(v.z > 0) << (g*4 + 2);
        m |= (uint_t)(v.w > 0) << (g*4 + 3);
    }
    abits[idx] = m;
}

// ---- gemm1 via MFMA (bf16 hi/lo split): h = x @ W_all, FUSED scores1.
// grid (64, 8): x = i-block (64 rows), y = head. block 256 = 4 waves (16 rows each).
// Writes hT bf16 [512][4096] + ssrc2/sdst2 (pre-scaled log2e). No f32 h output.
__global__ __launch_bounds__(256) void k_gemm1(
        const ushort_t* __restrict__ xh, const ushort_t* __restrict__ xl,
        const ushort_t* __restrict__ Wh, const ushort_t* __restrict__ Wl,
        const float* __restrict__ aatt,
        ushort_t* __restrict__ hT,
        float* __restrict__ ssrc2, float* __restrict__ sdst2){
    const int t = threadIdx.x;
    const int l = t & 63, wv = t >> 6;
    const int lr = l & 15, lg = l >> 4;
    const int ib = blockIdx.x*64 + wv*16;
    const int hd = blockIdx.y;
    const int j0 = hd*64;

    f32x4 acc[4] = {};
    #pragma unroll 2
    for(int ks=0; ks<16; ks++){
        const int kb = ks*32 + lg*8;
        bf16x8 ah = *(const bf16x8*)&xh[(size_t)(ib+lr)*512 + kb];
        bf16x8 al = *(const bf16x8*)&xl[(size_t)(ib+lr)*512 + kb];
        bf16x8 bh[4], bl[4];
        #pragma unroll
        for(int nt=0;nt<4;nt++){
            bh[nt] = *(const bf16x8*)&Wh[(size_t)(j0+nt*16+lr)*512 + kb];
            bl[nt] = *(const bf16x8*)&Wl[(size_t)(j0+nt*16+lr)*512 + kb];
        }
        #pragma unroll
        for(int nt=0;nt<4;nt++){
            acc[nt] = __builtin_amdgcn_mfma_f32_16x16x32_bf16(ah, bh[nt], acc[nt], 0,0,0);
            acc[nt] = __builtin_amdgcn_mfma_f32_16x16x32_bf16(al, bh[nt], acc[nt], 0,0,0);
            acc[nt] = __builtin_amdgcn_mfma_f32_16x16x32_bf16(ah, bl[nt], acc[nt], 0,0,0);
        }
    }
    // hT bf16 write (row = feature col, contiguous in i)
    #pragma unroll
    for(int nt=0;nt<4;nt++){
        const int col = j0 + nt*16 + lr;
        ushort4 o;
        o.x = f2bf(acc[nt][0]); o.y = f2bf(acc[nt][1]);
        o.z = f2bf(acc[nt][2]); o.w = f2bf(acc[nt][3]);
        *(ushort4*)&hT[(size_t)col*NN + ib + lg*4] = o;
    }
    // fused scores: s_src/s_dst per row, reduce over lr lanes
    float a1v[4], a2v[4];
    #pragma unroll
    for(int nt=0;nt<4;nt++){
        a1v[nt] = aatt[hd*128 + nt*16 + lr];
        a2v[nt] = aatt[hd*128 + 64 + nt*16 + lr];
    }
    #pragma unroll
    for(int r=0;r<4;r++){
        float ps = acc[0][r]*a1v[0] + acc[1][r]*a1v[1] + acc[2][r]*a1v[2] + acc[3][r]*a1v[3];
        float pd = acc[0][r]*a2v[0] + acc[1][r]*a2v[1] + acc[2][r]*a2v[2] + acc[3][r]*a2v[3];
        #pragma unroll
        for(int m=1;m<16;m<<=1){
            ps += __shfl_xor(ps, m);
            pd += __shfl_xor(pd, m);
        }
        if (lr == 0){
            ssrc2[hd*NN + ib + lg*4 + r] = ps*LOG2E;
            sdst2[hd*NN + ib + lg*4 + r] = pd*LOG2E;
        }
    }
}

// ---- attention layer1 via MFMA, 2-deep pipeline, i-tile 64, 1 head/block.
// grid (64, 4, 8): i-block(64), j-chunk(1024), head. block 256 = 4 waves.
// Waves split the j-chunk 4-way (256 j each, 8 jt); LDS-reduce epilogue.
__global__ __launch_bounds__(256) void k_attn1(
        const ushort_t* __restrict__ hT,
        const float* __restrict__ ssrc2, const float* __restrict__ sdst2,
        const uchar_t* __restrict__ abits,
        float* __restrict__ pnumT, float* __restrict__ pden){
    const int t = threadIdx.x;
    const int l = t & 63, wv = t >> 6;
    const int hd = blockIdx.z;
    const int i0 = blockIdx.x*64;
    const int jcc = blockIdx.y;
    const int lr = l & 15, lg = l >> 4;

    f32x4 acc[4][4] = {};   // [mh][nt]
    f32x4 dacc[4] = {};

    float ss[4];
    #pragma unroll
    for(int mh=0;mh<4;mh++)
        ss[mh] = ssrc2[hd*NN + i0 + mh*16 + lr];

    bf16x8 ones;
    #pragma unroll
    for(int e=0;e<8;e++) ones[e] = (__bf16)1.0f;

    const int jwb = jcc*1024 + wv*256;                 // wave's j base (8 jt of 32)
    const uchar_t* arow[4];
    #pragma unroll
    for(int mh=0;mh<4;mh++)
        arow[mh] = &abits[(size_t)(i0 + mh*16 + lr)*512 + (jwb >> 3)];

    bf16x8 bA[4], bB[4];
    float4 sdaA, sdbA, sdaB, sdbB;
    uint_t bitsA[4], bitsB[4];

#define LOAD1(SFX, JT) { \
    const int jb_ = jwb + (JT)*32 + lg*8; \
    _Pragma("unroll") \
    for(int nt=0;nt<4;nt++) \
        b##SFX[nt] = *(const bf16x8*)&hT[(size_t)(hd*64 + nt*16 + lr)*NN + jb_]; \
    sda##SFX = *(const float4*)&sdst2[hd*NN + jb_]; \
    sdb##SFX = *(const float4*)&sdst2[hd*NN + jb_ + 4]; \
    _Pragma("unroll") \
    for(int mh=0;mh<4;mh++) \
        bits##SFX[mh] = arow[mh][(JT)*4 + lg]; }

#define COMP1(SFX) { \
    float sdv[8] = {sda##SFX.x, sda##SFX.y, sda##SFX.z, sda##SFX.w, \
                    sdb##SFX.x, sdb##SFX.y, sdb##SFX.z, sdb##SFX.w}; \
    _Pragma("unroll") \
    for(int mh=0;mh<4;mh++){ \
        const uint_t bits = bits##SFX[mh]; \
        bf16x8 a; \
        _Pragma("unroll") \
        for(int e=0;e<8;e++){ \
            float s_ = ss[mh] + sdv[e]; \
            float t_ = fmaxf(s_, 0.2f*s_); \
            float w_ = EXP2(t_) * (float)((bits >> e) & 1u); \
            a[e] = (__bf16)w_; \
        } \
        _Pragma("unroll") \
        for(int nt=0;nt<4;nt++) \
            acc[mh][nt] = __builtin_amdgcn_mfma_f32_16x16x32_bf16( \
                a, b##SFX[nt], acc[mh][nt], 0, 0, 0); \
        dacc[mh] = __builtin_amdgcn_mfma_f32_16x16x32_bf16( \
                a, ones, dacc[mh], 0, 0, 0); \
    } }

    LOAD1(A, 0);
    for(int jt=0; jt<8; jt+=2){
        LOAD1(B, jt+1);
        COMP1(A);
        if (jt + 2 < 8) LOAD1(A, jt+2);
        COMP1(B);
    }
#undef LOAD1
#undef COMP1

    // cross-wave reduction in LDS: slots 0..15 = acc[mh*4+nt], 16..19 = dacc[mh]
    __shared__ f32x4 red[2][20][64];
    __syncthreads();
    if (wv >= 2){
        #pragma unroll
        for(int mh=0;mh<4;mh++){
            #pragma unroll
            for(int nt=0;nt<4;nt++) red[wv-2][mh*4+nt][l] = acc[mh][nt];
            red[wv-2][16+mh][l] = dacc[mh];
        }
    }
    __syncthreads();
    if (wv < 2){
        #pragma unroll
        for(int mh=0;mh<4;mh++){
            #pragma unroll
            for(int nt=0;nt<4;nt++) acc[mh][nt] += red[wv][mh*4+nt][l];
            dacc[mh] += red[wv][16+mh][l];
        }
    }
    __syncthreads();
    if (wv == 1){
        #pragma unroll
        for(int mh=0;mh<4;mh++){
            #pragma unroll
            for(int nt=0;nt<4;nt++) red[0][mh*4+nt][l] = acc[mh][nt];
            red[0][16+mh][l] = dacc[mh];
        }
    }
    __syncthreads();
    if (wv == 0){
        #pragma unroll
        for(int mh=0;mh<4;mh++){
            #pragma unroll
            for(int nt=0;nt<4;nt++){
                f32x4 v = acc[mh][nt] + red[0][mh*4+nt][l];
                int col = hd*64 + nt*16 + lr;
                float4 o = {v[0], v[1], v[2], v[3]};
                *(float4*)&pnumT[((size_t)jcc*512 + col)*NN + i0 + mh*16 + lg*4] = o;
            }
            f32x4 d = dacc[mh] + red[0][16+mh][l];
            if (lr == 0){
                #pragma unroll
                for(int r=0;r<4;r++)
                    pden[((size_t)jcc*8 + hd)*NN + i0 + mh*16 + lg*4 + r] = d[r];
            }
        }
    }
}

// ---- reduce layer1: hcatT[c][i] = elu( sum_jc pnumT / sum_jc pden )
__global__ void k_reduce1T(const float* __restrict__ pnumT, const float* __restrict__ pden,
                           float* __restrict__ hcatT){
    int idx = blockIdx.x*256 + threadIdx.x;           // < 512*4096
    int c = idx >> 12, i = idx & 4095, hd = c >> 6;
    float s = 0.f, d = 0.f;
    #pragma unroll
    for(int jc=0;jc<4;jc++){
        s += pnumT[((size_t)jc*512 + c)*NN + i];
        d += pden[((size_t)jc*8 + hd)*NN + i];
    }
    hcatT[(size_t)c*NN + i] = elu1(s/d);
}

// ---- gemm2 fused: h2 = hcat @ Wout; emits h2T bf16 + ss2/sd2 (scores, *log2e)
__global__ __launch_bounds__(256) void k_gemm2(const float* __restrict__ AT,
                                               const float* __restrict__ B,
                                               const float* __restrict__ aout,
                                               ushort_t* __restrict__ h2T,
                                               float* __restrict__ ss2,
                                               float* __restrict__ sd2){
    __shared__ float As[32][32];   // [k][i]
    __shared__ float Bs[32][32];   // [k][n]
    const int t = threadIdx.x;
    const int i0 = blockIdx.x*32;
    const int ty = t >> 4, tx = t & 15;
    float acc[2][2] = {{0.f,0.f},{0.f,0.f}};
    for(int k0=0;k0<512;k0+=32){
        __syncthreads();
        { int k = t >> 3, i4 = (t & 7)*4;
          *(float4*)&As[k][i4] = *(const float4*)&AT[(size_t)(k0+k)*NN + i0 + i4]; }
        { int k = t >> 3, n4 = (t & 7)*4;
          *(float4*)&Bs[k][n4] = *(const float4*)&B[(size_t)(k0+k)*32 + n4]; }
        __syncthreads();
        #pragma unroll
        for(int k=0;k<32;k++){
            float2 a2 = *(const float2*)&As[k][ty*2];
            float2 b2 = *(const float2*)&Bs[k][tx*2];
            acc[0][0] += a2.x*b2.x; acc[0][1] += a2.x*b2.y;
            acc[1][0] += a2.y*b2.x; acc[1][1] += a2.y*b2.y;
        }
    }
    // h2T bf16 writes
    #pragma unroll
    for(int a=0;a<2;a++){
        #pragma unroll
        for(int b=0;b<2;b++)
            h2T[(size_t)(tx*2+b)*NN + i0 + ty*2 + a] = f2bf(acc[a][b]);
    }
    // fused scores: reduce over tx (16 lanes)
    float a1x = aout[tx*2], a1y = aout[tx*2+1];
    float a2x = aout[32+tx*2], a2y = aout[32+tx*2+1];
    #pragma unroll
    for(int a=0;a<2;a++){
        float ps = acc[a][0]*a1x + acc[a][1]*a1y;
        float pd = acc[a][0]*a2x + acc[a][1]*a2y;
        #pragma unroll
        for(int m=1;m<16;m<<=1){
            ps += __shfl_xor(ps, m);
            pd += __shfl_xor(pd, m);
        }
        if (tx == 0){
            ss2[i0 + ty*2 + a] = ps*LOG2E;
            sd2[i0 + ty*2 + a] = pd*LOG2E;
        }
    }
}

// ---- attention layer2 via MFMA, 2-deep pipeline, i-tile 64.
// grid (64, 8): i-block(64), j-chunk(512). 4 waves split chunk (128 j = 4 jt each).
__global__ __launch_bounds__(256) void k_attn2(
        const ushort_t* __restrict__ h2T,
        const float* __restrict__ ss2, const float* __restrict__ sd2,
        const uchar_t* __restrict__ abits,
        float* __restrict__ pnum2T, float* __restrict__ pden2){
    const int t = threadIdx.x;
    const int l = t & 63, wv = t >> 6;
    const int i0 = blockIdx.x*64;
    const int jc = blockIdx.y;
    const int lr = l & 15, lg = l >> 4;

    f32x4 acc[4][2] = {};   // [mh][nt]
    f32x4 dacc[4] = {};

    float ss[4];
    #pragma unroll
    for(int mh=0;mh<4;mh++)
        ss[mh] = ss2[i0 + mh*16 + lr];

    bf16x8 ones;
    #pragma unroll
    for(int e=0;e<8;e++) ones[e] = (__bf16)1.0f;

    const int jwb = jc*512 + wv*128;          // 4 jt of 32
    const uchar_t* arow[4];
    #pragma unroll
    for(int mh=0;mh<4;mh++)
        arow[mh] = &abits[(size_t)(i0 + mh*16 + lr)*512 + (jwb >> 3)];

    bf16x8 bA[2], bB[2];
    float4 sdaA, sdbA, sdaB, sdbB;
    uint_t bitsA[4], bitsB[4];

#define LOAD2(SFX, JT) { \
    const int jb_ = jwb + (JT)*32 + lg*8; \
    _Pragma("unroll") \
    for(int nt=0;nt<2;nt++) \
        b##SFX[nt] = *(const bf16x8*)&h2T[(size_t)(nt*16 + lr)*NN + jb_]; \
    sda##SFX = *(const float4*)&sd2[jb_]; \
    sdb##SFX = *(const float4*)&sd2[jb_ + 4]; \
    _Pragma("unroll") \
    for(int mh=0;mh<4;mh++) \
        bits##SFX[mh] = arow[mh][(JT)*4 + lg]; }

#define COMP2(SFX) { \
    float sdv[8] = {sda##SFX.x, sda##SFX.y, sda##SFX.z, sda##SFX.w, \
                    sdb##SFX.x, sdb##SFX.y, sdb##SFX.z, sdb##SFX.w}; \
    _Pragma("unroll") \
    for(int mh=0;mh<4;mh++){ \
        const uint_t bits = bits##SFX[mh]; \
        bf16x8 a; \
        _Pragma("unroll") \
        for(int e=0;e<8;e++){ \
            float s_ = ss[mh] + sdv[e]; \
            float t_ = fmaxf(s_, 0.2f*s_); \
            float w_ = EXP2(t_) * (float)((bits >> e) & 1u); \
            a[e] = (__bf16)w_; \
        } \
        _Pragma("unroll") \
        for(int nt=0;nt<2;nt++) \
            acc[mh][nt] = __builtin_amdgcn_mfma_f32_16x16x32_bf16( \
                a, b##SFX[nt], acc[mh][nt], 0, 0, 0); \
        dacc[mh] = __builtin_amdgcn_mfma_f32_16x16x32_bf16( \
                a, ones, dacc[mh], 0, 0, 0); \
    } }

    LOAD2(A, 0);
    for(int jt=0; jt<4; jt+=2){
        LOAD2(B, jt+1);
        COMP2(A);
        if (jt + 2 < 4) LOAD2(A, jt+2);
        COMP2(B);
    }
#undef LOAD2
#undef COMP2

    // cross-wave LDS reduce: slots 0..7 acc[mh*2+nt], 8..11 dacc[mh]
    __shared__ f32x4 red2[2][12][64];
    __syncthreads();
    if (wv >= 2){
        #pragma unroll
        for(int mh=0;mh<4;mh++){
            #pragma unroll
            for(int nt=0;nt<2;nt++) red2[wv-2][mh*2+nt][l] = acc[mh][nt];
            red2[wv-2][8+mh][l] = dacc[mh];
        }
    }
    __syncthreads();
    if (wv < 2){
        #pragma unroll
        for(int mh=0;mh<4;mh++){
            #pragma unroll
            for(int nt=0;nt<2;nt++) acc[mh][nt] += red2[wv][mh*2+nt][l];
            dacc[mh] += red2[wv][8+mh][l];
        }
    }
    __syncthreads();
    if (wv == 1){
        #pragma unroll
        for(int mh=0;mh<4;mh++){
            #pragma unroll
            for(int nt=0;nt<2;nt++) red2[0][mh*2+nt][l] = acc[mh][nt];
            red2[0][8+mh][l] = dacc[mh];
        }
    }
    __syncthreads();
    if (wv == 0){
        #pragma unroll
        for(int mh=0;mh<4;mh++){
            #pragma unroll
            for(int nt=0;nt<2;nt++){
                f32x4 v = acc[mh][nt] + red2[0][mh*2+nt][l];
                int col = nt*16 + lr;
                float4 o = {v[0], v[1], v[2], v[3]};
                *(float4*)&pnum2T[((size_t)jc*32 + col)*NN + i0 + mh*16 + lg*4] = o;
            }
            f32x4 d = dacc[mh] + red2[0][8+mh][l];
            if (lr == 0){
                #pragma unroll
                for(int r=0;r<4;r++)
                    pden2[(size_t)jc*NN + i0 + mh*16 + lg*4 + r] = d[r];
            }
        }
    }
}

// ---- reduce layer2 -> final output
__global__ void k_reduce2(const float* __restrict__ pnum2T, const float* __restrict__ pden2,
                          float* __restrict__ out){
    int idx = blockIdx.x*256 + threadIdx.x;       // < 32*4096
    int c = idx >> 12, i = idx & 4095;
    float s = 0.f, d = 0.f;
    #pragma unroll
    for(int jc=0;jc<8;jc++){
        s += pnum2T[((size_t)jc*32 + c)*NN + i];
        d += pden2[(size_t)jc*NN + i];
    }
    out[(size_t)i*32 + c] = elu1(s/d);
}

extern "C" void kernel_launch(void* const* d_in, const int* in_sizes, int n_in,
                              void* d_out, int out_size, void* d_ws, size_t ws_size,
                              hipStream_t stream){
    const float* x    = (const float*)d_in[0];
    const int*   adj  = (const int*)  d_in[1];
    const float* Watt = (const float*)d_in[2];
    const float* aatt = (const float*)d_in[3];
    const float* Wout = (const float*)d_in[4];
    const float* aout = (const float*)d_in[5];
    float* out = (float*)d_out;
    char* ws = (char*)d_ws;

    float*    hcatT = (float*)   (ws + (size_t) 0*MB);  // 8 MB [512][4096]
    ushort_t* Whi   = (ushort_t*)(ws + (size_t) 8*MB);  // 512 KB [512][512] bf16
    ushort_t* Wlo   = (ushort_t*)(ws + (size_t) 8*MB + 512*1024);  // 512 KB
    float*    ssrc2 = (float*)   (ws + (size_t) 9*MB);  // 128 KB [8][4096]
    float*    sdst2 = (float*)   (ws + (size_t)10*MB);  // 128 KB
    ushort_t* hT    = (ushort_t*)(ws + (size_t)11*MB);  // 4 MB [512][4096] bf16
    uint_t*   abits = (uint_t*)  (ws + (size_t)15*MB);  // 2 MB [4096][128]
    float*    ss2   = (float*)   (ws + (size_t)18*MB);  // 16 KB
    float*    sd2   = (float*)   (ws + (size_t)19*MB);  // 16 KB
    ushort_t* h2T   = (ushort_t*)(ws + (size_t)20*MB);  // 256 KB [32][4096] bf16
    float*    pden  = (float*)   (ws + (size_t)21*MB);  // 512 KB [4][8][4096]
    float*    pden2 = (float*)   (ws + (size_t)21*MB + 512*1024); // 128 KB [8][4096]
    float*    pnumT = (float*)   (ws + (size_t)22*MB);  // 32 MB [4][512][4096] (22..54)
    float*    pnum2T= pnumT;                            // reused: [8][32][4096] 4MB
    // xh/xl overlay pnumT's tail: consumed by gemm1 BEFORE attn1 writes pnumT
    ushort_t* xh    = (ushort_t*)(ws + (size_t)46*MB);  // 4 MB [4096][512] bf16
    ushort_t* xl    = (ushort_t*)(ws + (size_t)50*MB);  // 4 MB
    if (ws_size < (size_t)55*MB) return;                // need 55 MB scratch

    k_prepW   <<<256, 256, 0, stream>>>(Watt, Whi, Wlo);
    k_splitx  <<<2048, 256, 0, stream>>>(x, xh, xl);
    k_pack    <<<2048, 256, 0, stream>>>(adj, abits);
    k_gemm1   <<<dim3(64,8), 256, 0, stream>>>(xh, xl, Whi, Wlo, aatt, hT, ssrc2, sdst2);
    k_attn1   <<<dim3(64,4,8), 256, 0, stream>>>(hT, ssrc2, sdst2, (const uchar_t*)abits, pnumT, pden);
    k_reduce1T<<<8192, 256, 0, stream>>>(pnumT, pden, hcatT);
    k_gemm2   <<<128, 256, 0, stream>>>(hcatT, Wout, aout, h2T, ss2, sd2);
    k_attn2   <<<dim3(64,8), 256, 0, stream>>>(h2T, ss2, sd2, (const uchar_t*)abits, pnum2T, pden2);
    k_reduce2 <<<512, 256, 0, stream>>>(pnum2T, pden2, out);
}